// Round 4
// baseline (3263.440 us; speedup 1.0000x reference)
//
#include <hip/hip_runtime.h>
#include <math.h>

#define NN 100000
#define NE 1600000
#define NG 1024
#define ET (NE + NN)   // edges + self loops = 1,700,000

// ---------- order-preserving float<->uint encoding for atomic max ----------
__device__ __forceinline__ unsigned enc_f(float f) {
    unsigned u = __float_as_uint(f);
    return (u & 0x80000000u) ? ~u : (u | 0x80000000u);
}
__device__ __forceinline__ float dec_f(unsigned u) {
    return (u & 0x80000000u) ? __uint_as_float(u & 0x7FFFFFFFu)
                             : __uint_as_float(~u);
}

// ---------- h = in @ W   (in: [NN,CIN], W: [CIN,COUT], h: [NN,COUT]) ----------
template <int CIN, int COUT>
__global__ void proj_kernel(const float* __restrict__ in, const float* __restrict__ W,
                            float* __restrict__ out) {
    int idx = blockIdx.x * blockDim.x + threadIdx.x;
    if (idx >= NN * COUT) return;
    int n = idx / COUT, c = idx % COUT;
    float acc = 0.f;
#pragma unroll 4
    for (int k = 0; k < CIN; ++k) acc += in[n * CIN + k] * W[k * COUT + c];
    out[idx] = acc;
}

// ---------- e_src/e_dst per (node, head), F runtime (non-hot kernel) ----------
__global__ void attn_kernel(const float* __restrict__ h, const float* __restrict__ asr,
                            const float* __restrict__ adt, int F,
                            float* __restrict__ es, float* __restrict__ ed) {
    int idx = blockIdx.x * blockDim.x + threadIdx.x;
    if (idx >= NN * 8) return;
    int n = idx >> 3, hd = idx & 7;
    const float* hp = h + (n * 8 + hd) * F;
    float s = 0.f, d = 0.f;
    for (int f = 0; f < F; ++f) {
        float v = hp[f];
        s += v * asr[hd * F + f];
        d += v * adt[hd * F + f];
    }
    es[idx] = s;
    ed[idx] = d;
}

__device__ __forceinline__ void edge_sd(int e, const int* __restrict__ src,
                                        const int* __restrict__ dst, int& s, int& d) {
    if (e < NE) { s = src[e]; d = dst[e]; }
    else        { s = d = e - NE; }   // self loops
}

// ---------- pass 1: segment max ----------
__global__ void edge_max_kernel(const int* __restrict__ src, const int* __restrict__ dst,
                                const float* __restrict__ es, const float* __restrict__ ed,
                                unsigned* __restrict__ mu) {
    int idx = blockIdx.x * blockDim.x + threadIdx.x;
    if (idx >= ET * 8) return;
    int e = idx >> 3, hd = idx & 7;
    int s, d; edge_sd(e, src, dst, s, d);
    float el = es[s * 8 + hd] + ed[d * 8 + hd];
    el = el > 0.f ? el : 0.2f * el;   // leaky relu
    atomicMax(mu + d * 8 + hd, enc_f(el));
}

__global__ void decode_kernel(unsigned* __restrict__ mu, int n) {
    int idx = blockIdx.x * blockDim.x + threadIdx.x;
    if (idx >= n) return;
    unsigned u = mu[idx];
    ((float*)mu)[idx] = dec_f(u);
}

// ---------- pass 2: denominator ----------
__global__ void edge_sum_kernel(const int* __restrict__ src, const int* __restrict__ dst,
                                const float* __restrict__ es, const float* __restrict__ ed,
                                const float* __restrict__ m, float* __restrict__ den) {
    int idx = blockIdx.x * blockDim.x + threadIdx.x;
    if (idx >= ET * 8) return;
    int e = idx >> 3, hd = idx & 7;
    int s, d; edge_sd(e, src, dst, s, d);
    float el = es[s * 8 + hd] + ed[d * 8 + hd];
    el = el > 0.f ? el : 0.2f * el;
    atomicAdd(den + d * 8 + hd, expf(el - m[d * 8 + hd]));
}

// ---------- pass 3: weighted aggregation ----------
template <int F>
__global__ void edge_accum_kernel(const int* __restrict__ src, const int* __restrict__ dst,
                                  const float* __restrict__ es, const float* __restrict__ ed,
                                  const float* __restrict__ m, const float* __restrict__ den,
                                  const float* __restrict__ h, float* __restrict__ out) {
    constexpr int HF = 8 * F;
    int idx = blockIdx.x * blockDim.x + threadIdx.x;
    if (idx >= ET * HF) return;
    int e = idx / HF, c = idx % HF;
    int hd = c / F;
    int s, d; edge_sd(e, src, dst, s, d);
    float el = es[s * 8 + hd] + ed[d * 8 + hd];
    el = el > 0.f ? el : 0.2f * el;
    float alpha = expf(el - m[d * 8 + hd]) / den[d * 8 + hd];
    atomicAdd(out + d * HF + c, alpha * h[s * HF + c]);
}

// ---------- bias + ELU (in place ok), HF runtime ----------
__global__ void bias_elu_kernel(const float* __restrict__ in, const float* __restrict__ b,
                                int HF, float* __restrict__ out) {
    int idx = blockIdx.x * blockDim.x + threadIdx.x;
    if (idx >= NN * HF) return;
    int c = idx % HF;
    float v = in[idx] + b[c];
    out[idx] = v > 0.f ? v : expm1f(v);
}

// ---------- global mean pool ----------
__global__ void pool_kernel(const float* __restrict__ h, const int* __restrict__ batch,
                            float* __restrict__ gsum, float* __restrict__ gcnt) {
    int idx = blockIdx.x * blockDim.x + threadIdx.x;
    if (idx >= NN * 128) return;
    int n = idx >> 7, c = idx & 127;
    int g = batch[n];
    atomicAdd(gsum + g * 128 + c, h[idx]);
    if (c == 0) atomicAdd(gcnt + g, 1.0f);
}

// ---------- BN + fc1 + relu + fc2 + log_softmax ----------
__global__ void head_kernel(const float* __restrict__ gsum, const float* __restrict__ gcnt,
                            const float* __restrict__ bn_g, const float* __restrict__ bn_b,
                            const float* __restrict__ bn_m, const float* __restrict__ bn_v,
                            const float* __restrict__ w1, const float* __restrict__ b1,
                            const float* __restrict__ w2, const float* __restrict__ b2,
                            float* __restrict__ out) {
    __shared__ float sg[128];
    __shared__ float sh[32];
    __shared__ float so[10];
    __shared__ float red[2];
    int g = blockIdx.x, t = threadIdx.x;
    float cnt = fmaxf(gcnt[g], 1.0f);
    if (t < 128) {
        float v = gsum[g * 128 + t] / cnt;
        v = (v - bn_m[t]) * rsqrtf(bn_v[t] + 1e-5f) * bn_g[t] + bn_b[t];
        sg[t] = v;
    }
    __syncthreads();
    if (t < 32) {
        float acc = b1[t];
        for (int k = 0; k < 128; ++k) acc += sg[k] * w1[k * 32 + t];
        sh[t] = fmaxf(acc, 0.f);
    }
    __syncthreads();
    if (t < 10) {
        float acc = b2[t];
        for (int k = 0; k < 32; ++k) acc += sh[k] * w2[k * 10 + t];
        so[t] = acc;
    }
    __syncthreads();
    if (t == 0) {
        float mx = -1e30f;
        for (int i = 0; i < 10; ++i) mx = fmaxf(mx, so[i]);
        float se = 0.f;
        for (int i = 0; i < 10; ++i) se += expf(so[i] - mx);
        red[0] = mx;
        red[1] = logf(se);
    }
    __syncthreads();
    if (t < 10) out[g * 10 + t] = so[t] - red[0] - red[1];
}

// ---------- one GAT layer ----------
template <int CIN, int F>
static void run_layer(const float* hin, const float* W, const float* as_, const float* ad_,
                      const float* bias, const int* src, const int* dst,
                      float* A, float* B, float* es, float* ed, float* m, float* den,
                      hipStream_t stream) {
    constexpr int HF = 8 * F;
    const int T = 256;
    proj_kernel<CIN, HF><<<(NN * HF + T - 1) / T, T, 0, stream>>>(hin, W, A);
    attn_kernel<<<(NN * 8 + T - 1) / T, T, 0, stream>>>(A, as_, ad_, F, es, ed);
    (void)hipMemsetAsync(m, 0, NN * 8 * sizeof(float), stream);    // 0 == encoded -inf
    (void)hipMemsetAsync(den, 0, NN * 8 * sizeof(float), stream);
    (void)hipMemsetAsync(B, 0, NN * HF * sizeof(float), stream);
    edge_max_kernel<<<(ET * 8 + T - 1) / T, T, 0, stream>>>(src, dst, es, ed, (unsigned*)m);
    decode_kernel<<<(NN * 8 + T - 1) / T, T, 0, stream>>>((unsigned*)m, NN * 8);
    edge_sum_kernel<<<(ET * 8 + T - 1) / T, T, 0, stream>>>(src, dst, es, ed, m, den);
    edge_accum_kernel<F><<<(ET * HF + T - 1) / T, T, 0, stream>>>(src, dst, es, ed, m, den, A, B);
    bias_elu_kernel<<<(NN * HF + T - 1) / T, T, 0, stream>>>(B, bias, HF, B);
}

extern "C" void kernel_launch(void* const* d_in, const int* in_sizes, int n_in,
                              void* d_out, int out_size, void* d_ws, size_t ws_size,
                              hipStream_t stream) {
    const float* x     = (const float*)d_in[0];
    const int*   ei    = (const int*)d_in[1];
    const int*   batch = (const int*)d_in[2];
    const float* W1  = (const float*)d_in[3];
    const float* as1 = (const float*)d_in[4];
    const float* ad1 = (const float*)d_in[5];
    const float* b1  = (const float*)d_in[6];
    const float* W2  = (const float*)d_in[7];
    const float* as2 = (const float*)d_in[8];
    const float* ad2 = (const float*)d_in[9];
    const float* b2  = (const float*)d_in[10];
    const float* W3  = (const float*)d_in[11];
    const float* as3 = (const float*)d_in[12];
    const float* ad3 = (const float*)d_in[13];
    const float* b3  = (const float*)d_in[14];
    const float* bn_g = (const float*)d_in[15];
    const float* bn_b = (const float*)d_in[16];
    const float* bn_m = (const float*)d_in[17];
    const float* bn_v = (const float*)d_in[18];
    const float* fc1w = (const float*)d_in[19];
    const float* fc1b = (const float*)d_in[20];
    const float* fc2w = (const float*)d_in[21];
    const float* fc2b = (const float*)d_in[22];

    const int* src = ei;          // row 0
    const int* dst = ei + NE;     // row 1

    float* A    = (float*)d_ws;          // [NN,128] projected h
    float* B    = A + NN * 128;          // [NN,128] accum / layer output
    float* es   = B + NN * 128;          // [NN,8]
    float* ed   = es + NN * 8;
    float* m    = ed + NN * 8;
    float* den  = m + NN * 8;
    float* gsum = den + NN * 8;          // [NG,128]
    float* gcnt = gsum + NG * 128;       // [NG]

    // layer 1: in=2 -> 8x8=64 ; layer 2: 64 -> 8x16=128 ; layer 3: 128 -> 128
    run_layer<2, 8>(x, W1, as1, ad1, b1, src, dst, A, B, es, ed, m, den, stream);
    run_layer<64, 16>(B, W2, as2, ad2, b2, src, dst, A, B, es, ed, m, den, stream);
    run_layer<128, 16>(B, W3, as3, ad3, b3, src, dst, A, B, es, ed, m, den, stream);

    const int T = 256;
    (void)hipMemsetAsync(gsum, 0, NG * 128 * sizeof(float), stream);
    (void)hipMemsetAsync(gcnt, 0, NG * sizeof(float), stream);
    pool_kernel<<<(NN * 128 + T - 1) / T, T, 0, stream>>>(B, batch, gsum, gcnt);
    head_kernel<<<NG, 128, 0, stream>>>(gsum, gcnt, bn_g, bn_b, bn_m, bn_v,
                                        fc1w, fc1b, fc2w, fc2b, (float*)d_out);
}